// Round 8
// baseline (33.014 us; speedup 1.0000x reference)
//
#include <hip/hip_runtime.h>

// Problem constants (from reference): B=32, C=4, L=512
constexpr int B = 32;
constexpr int C = 4;
constexpr int L = 512;
constexpr int THREADS = 256;   // 4 waves
constexpr int KSPLIT = 16;     // blocks per plane -> grid = 16*128 = 2048 blocks

// Unaligned-tolerant 16B load (both streams are only dword-aligned).
__device__ inline float4 ld4u(const float* p) {
    float4 v;
    __builtin_memcpy(&v, p, sizeof(float4));
    return v;
}

// Stage 1, balanced partition: block (k, bc) processes an exact 1/KSPLIT share
// of plane bc's VALID row range [x0,x1). Every block does identical work:
// no masked rows, no early-exit churn, exactly one scheduling round (2048
// blocks). blockIdx.x = k fastest keeps resident blocks on contiguous rows.
__global__ __launch_bounds__(THREADS)
void imgmul_stage1(const float* __restrict__ receptor,
                   const float* __restrict__ ligand,
                   const int* __restrict__ T,
                   float* __restrict__ partials)
{
    const int k  = blockIdx.x;           // 0..KSPLIT-1
    const int bc = blockIdx.y;           // 0..B*C-1
    const int b  = bc >> 2;              // C == 4
    const int dx = T[2 * b + 0];
    const int dy = T[2 * b + 1];

    const int x0 = dx > 0 ? dx : 0;
    const int x1 = (L + dx) < L ? (L + dx) : L;
    const int y0 = dy > 0 ? dy : 0;
    const int y1 = (L + dy) < L ? (L + dy) : L;
    const int W  = y1 - y0;              // 256..512
    const int nv = x1 - x0;              // 256..512 valid rows

    // This block's exact share of valid rows.
    const int rb = x0 + (nv * k) / KSPLIT;
    const int re = x0 + (nv * (k + 1)) / KSPLIT;

    const size_t plane = (size_t)bc * (L * L);
    const float* rec = receptor + plane;
    const float* lig = ligand + plane;

    const int wave = threadIdx.x >> 6;
    const int lane = threadIdx.x & 63;

    // Per-lane column coordinates within the window (shared by all rows).
    // Pair-1 (first 256 columns of the window) is always fully valid (W>=256);
    // pair-2 is element-masked (only its last quad is partial).
    const int  yq0 = y0 + 4 * lane;
    const int  e2  = 256 + 4 * lane;
    const bool m0  = (e2 + 0) < W;
    const bool m1  = (e2 + 1) < W;
    const bool m2  = (e2 + 2) < W;
    const bool m3  = (e2 + 3) < W;
    const int  yq1 = m0 ? (y0 + e2) : y0;    // clamp fully-invalid quads

    float acc = 0.0f;
    for (int x = rb + wave; x < re; x += 4) {
        const float* rrow = rec + (size_t)x * L;
        const float* lrow = lig + (size_t)(x - dx) * L - dy; // lrow[y]=lig[x-dx][y-dy]

        const float4 a0 = ld4u(rrow + yq0);
        const float4 b0 = ld4u(lrow + yq0);
        const float4 a1 = ld4u(rrow + yq1);
        const float4 b1 = ld4u(lrow + yq1);

        float d = a0.x * b0.x;
        d = fmaf(a0.y, b0.y, d);
        d = fmaf(a0.z, b0.z, d);
        d = fmaf(a0.w, b0.w, d);
        d += (m0 ? a1.x * b1.x : 0.0f)
           + (m1 ? a1.y * b1.y : 0.0f)
           + (m2 ? a1.z * b1.z : 0.0f)
           + (m3 ? a1.w * b1.w : 0.0f);
        acc += d;
    }

    // ---- Wave reduce, then cross-wave via LDS ----
    #pragma unroll
    for (int off = 32; off > 0; off >>= 1)
        acc += __shfl_down(acc, off, 64);

    __shared__ float wsum[THREADS / 64];
    if (lane == 0) wsum[wave] = acc;
    __syncthreads();

    if (threadIdx.x == 0)
        partials[bc * KSPLIT + k] = wsum[0] + wsum[1] + wsum[2] + wsum[3];
}

// Stage 2: out[bc] = sum of its KSPLIT partials (one wave per output).
__global__ __launch_bounds__(64)
void imgmul_stage2(const float* __restrict__ partials, float* __restrict__ out)
{
    const int bc = blockIdx.x;
    const int lane = threadIdx.x & 63;
    float v = (lane < KSPLIT) ? partials[bc * KSPLIT + lane] : 0.0f;
    #pragma unroll
    for (int off = 32; off > 0; off >>= 1)
        v += __shfl_down(v, off, 64);
    if (lane == 0) out[bc] = v;
}

extern "C" void kernel_launch(void* const* d_in, const int* in_sizes, int n_in,
                              void* d_out, int out_size, void* d_ws, size_t ws_size,
                              hipStream_t stream)
{
    const float* receptor = (const float*)d_in[0];
    const float* ligand   = (const float*)d_in[1];
    const int*   T        = (const int*)d_in[2];
    float* out      = (float*)d_out;
    float* partials = (float*)d_ws;      // B*C*KSPLIT = 2048 floats of scratch

    imgmul_stage1<<<dim3(KSPLIT, B * C), dim3(THREADS), 0, stream>>>(
        receptor, ligand, T, partials);
    imgmul_stage2<<<dim3(B * C), dim3(64), 0, stream>>>(partials, out);
}